// Round 7
// baseline (148.628 us; speedup 1.0000x reference)
//
#include <hip/hip_runtime.h>
#include <hip/hip_fp16.h>
#include <math.h>

#define BDIM 4
#define LDIM 512
#define EDIM 1024
#define HDIM 128
#define TILE 31            // interior y-tile per block (s-grid is 32x32 with 1 halo)
#define NT   17            // 17*31 = 527 >= 512 tiles per spatial dim
#define K2   2.885390081777927f   // 2/ln(2): tanh(x) = 1 - 2/(exp2(K2*x)+1)
#define KC   64            // gemm K-chunk

typedef unsigned short ushort_t;
typedef __attribute__((ext_vector_type(8))) _Float16 half8;
typedef __attribute__((ext_vector_type(4))) float f32x4;

struct __align__(16) H8 { __half2 p[4]; };
struct __align__(8)  H4 { __half2 a, b; };

__device__ __forceinline__ float sum_h2(__half2 v) {
  return __low2float(v) + __high2float(v);
}

// ---------------------------------------------------------------------------
// Kernel 0: W1 (1024x128 f32, k-major) -> Wt (128x1024 f16, n-major).
// ---------------------------------------------------------------------------
__global__ __launch_bounds__(256) void wcvt(const float* __restrict__ W1,
                                            ushort_t* __restrict__ Wt) {
  const int g = (int)blockIdx.x * 256 + threadIdx.x;  // 0..16383
  const int n = g & 127, k8 = g >> 7;                 // k8: 0..127
  float v[8];
#pragma unroll
  for (int j = 0; j < 8; ++j) v[j] = W1[(size_t)(k8 * 8 + j) * HDIM + n];
  H8 o;
#pragma unroll
  for (int j = 0; j < 4; ++j) o.p[j] = __floats2half2_rn(v[2 * j], v[2 * j + 1]);
  *(H8*)&Wt[(size_t)n * EDIM + k8 * 8] = o;
}

// ---------------------------------------------------------------------------
// Kernel 1: hid = relu(emb @ W1 + b1) via f16 MFMA 16x16x32, f16 output
// (rec rows pre-scaled by K2). In-block split-K x2: 512 blocks x 512 threads;
// wave-group g = t>>8 covers K-half [g*512, g*512+512) in its own LDS buffers.
// 2 blocks/CU -> 4 waves/SIMD to hide the barrier vmcnt drains; serial chain
// is 8 chunks (was 16). Cross-group LDS reduce, then bias+relu+scale epilogue.
// ---------------------------------------------------------------------------
__global__ __launch_bounds__(512) void gemm_f16(
    const float* __restrict__ rec, const float* __restrict__ lig,
    const ushort_t* __restrict__ Wt, const float* __restrict__ b1,
    ushort_t* __restrict__ hid) {
  __shared__ ushort_t Wl[2][128][72];   // 18 KB per group
  __shared__ ushort_t Al[2][16][72];    // 2.25 KB per group
  const int t = threadIdx.x;
  const int g = t >> 8;                  // K-group 0/1
  const int u = t & 255;
  const int r0 = (int)blockIdx.x * 16;
  const int kbase = g * 512;
  const float* abase = (r0 < BDIM * LDIM)
                           ? rec + (size_t)r0 * EDIM
                           : lig + (size_t)(r0 - BDIM * LDIM) * EDIM;
  // staging: W row u>>1, 32 halves at (u&1)*32; A row u>>4, 4 floats at (u&15)*4
  const int wr = u >> 1, wko = (u & 1) * 32;
  const int am = u >> 4, ak4 = (u & 15) * 4;
  const ushort_t* wsrc = Wt + (size_t)wr * EDIM + kbase + wko;
  const float* asrc = abase + (size_t)am * EDIM + kbase + ak4;
  // frags (within group): 4 waves, wave wv owns cols [32wv, 32wv+32)
  const int l = u & 63, wv = u >> 6;
  const int kg = (l >> 4) * 8, m = l & 15;
  const int n0 = wv * 32 + m, n1 = n0 + 16;

  f32x4 acc0 = {0.f, 0.f, 0.f, 0.f}, acc1 = {0.f, 0.f, 0.f, 0.f};
  H8 wv0, wv1, wv2, wv3;
  float4 av;

#define LOADC(K0)                                                             \
  wv0 = *(const H8*)(wsrc + (K0));                                            \
  wv1 = *(const H8*)(wsrc + (K0) + 8);                                        \
  wv2 = *(const H8*)(wsrc + (K0) + 16);                                       \
  wv3 = *(const H8*)(wsrc + (K0) + 24);                                       \
  av = *(const float4*)(asrc + (K0));
#define WRITEC()                                                              \
  *(H8*)&Wl[g][wr][wko] = wv0;                                                \
  *(H8*)&Wl[g][wr][wko + 8] = wv1;                                            \
  *(H8*)&Wl[g][wr][wko + 16] = wv2;                                           \
  *(H8*)&Wl[g][wr][wko + 24] = wv3;                                           \
  {                                                                           \
    H4 ah;                                                                    \
    ah.a = __floats2half2_rn(av.x, av.y);                                     \
    ah.b = __floats2half2_rn(av.z, av.w);                                     \
    *(H4*)&Al[g][am][ak4] = ah;                                               \
  }

  LOADC(0)
  WRITEC()
  __syncthreads();
  for (int c = 0; c < 512 / KC; ++c) {
    if (c < 512 / KC - 1) LOADC((c + 1) * KC)   // prefetch
    half8 a0  = *(const half8*)&Al[g][m][kg];
    half8 a1  = *(const half8*)&Al[g][m][32 + kg];
    half8 b00 = *(const half8*)&Wl[g][n0][kg];
    half8 b01 = *(const half8*)&Wl[g][n0][32 + kg];
    half8 b10 = *(const half8*)&Wl[g][n1][kg];
    half8 b11 = *(const half8*)&Wl[g][n1][32 + kg];
    acc0 = __builtin_amdgcn_mfma_f32_16x16x32_f16(a0, b00, acc0, 0, 0, 0);
    acc1 = __builtin_amdgcn_mfma_f32_16x16x32_f16(a0, b10, acc1, 0, 0, 0);
    acc0 = __builtin_amdgcn_mfma_f32_16x16x32_f16(a1, b01, acc0, 0, 0, 0);
    acc1 = __builtin_amdgcn_mfma_f32_16x16x32_f16(a1, b11, acc1, 0, 0, 0);
    if (c < 512 / KC - 1) {
      __syncthreads();
      WRITEC()
      __syncthreads();
    }
  }
#undef LOADC
#undef WRITEC

  // cross-group reduce through LDS (reuse Wl space; 256x8 f32 = 8 KB)
  __syncthreads();
  float* red = (float*)&Wl[0][0][0];
  if (g == 1) {
#pragma unroll
    for (int k = 0; k < 4; ++k) {
      red[u * 8 + k]     = acc0[k];
      red[u * 8 + 4 + k] = acc1[k];
    }
  }
  __syncthreads();
  if (g == 0) {
#pragma unroll
    for (int k = 0; k < 4; ++k) {
      acc0[k] += red[u * 8 + k];
      acc1[k] += red[u * 8 + 4 + k];
    }
    // C/D: col = lane&15, row = (lane>>4)*4 + reg  [m89-verified]
    const float scale = (r0 < BDIM * LDIM) ? K2 : 1.0f;
    const int rbase = r0 + ((l >> 4) << 2);
    const int col0 = (wv << 5) + m;
#pragma unroll
    for (int nt = 0; nt < 2; ++nt) {
      const int col = col0 + nt * 16;
      const float bias = b1[col];
      f32x4 a = nt ? acc1 : acc0;
#pragma unroll
      for (int r = 0; r < 4; ++r) {
        float v = fmaxf(a[r] + bias, 0.f) * scale;
        ((_Float16*)hid)[(size_t)(rbase + r) * HDIM + col] = (_Float16)v;
      }
    }
  }
}

// ---------------------------------------------------------------------------
// Kernel 2: per 31x31 y-tile: s_k(p,q) = Wsum_k + sum_h (-2 w_k[h]) * g(p,q,h),
// g = rcp(1 + exp2(K2 * r_p[h] * l_q[h]))  (tanh folded through weights).
// f16 tiles + f16 tap grid -> 26.9 KB LDS -> 5 blocks/CU.
// ---------------------------------------------------------------------------
__global__ __launch_bounds__(256, 5) void bilinear_max(
    const ushort_t* __restrict__ hid, const float4* __restrict__ cw4,
    const float* __restrict__ cb, float* __restrict__ partial) {
  __shared__ ushort_t rl[32][136];   // 272 B row stride
  __shared__ ushort_t ll[32][136];
  __shared__ __half whl[4][HDIM];    // -2*w_k[h] as f16, h-contiguous
  __shared__ __half2 sl[32][33][2];  // taps {s00,s01},{s10,s11} per (p,q), f16
  __shared__ float wred[4];
  __shared__ float4 wpart[2];

  const int t = threadIdx.x;
  const int b = blockIdx.z;
  const int ib = (int)blockIdx.y * TILE - 1;
  const int jb = (int)blockIdx.x * TILE - 1;

  if (t < HDIM) {
    float4 w4 = cw4[t];
    whl[0][t] = __float2half(-2.f * w4.x);
    whl[1][t] = __float2half(-2.f * w4.y);
    whl[2][t] = __float2half(-2.f * w4.z);
    whl[3][t] = __float2half(-2.f * w4.w);
    float4 ws = w4;
#pragma unroll
    for (int off = 32; off > 0; off >>= 1) {
      ws.x += __shfl_down(ws.x, off, 64);
      ws.y += __shfl_down(ws.y, off, 64);
      ws.z += __shfl_down(ws.z, off, 64);
      ws.w += __shfl_down(ws.w, off, 64);
    }
    if ((t & 63) == 0) wpart[t >> 6] = ws;
  }
  H8 z;
  z.p[0] = z.p[1] = z.p[2] = z.p[3] = __floats2half2_rn(0.f, 0.f);
  for (int p = t; p < 1024; p += 256) {   // 64 rows x 16 b128 segments
    int r = p >> 4, seg = (p & 15) * 8;
    if (r < 32) {
      int i = ib + r;
      H8 v = z;
      if (i >= 0 && i < LDIM) v = *(const H8*)&hid[((size_t)(b * LDIM + i)) * HDIM + seg];
      *(H8*)&rl[r][seg] = v;
    } else {
      int j = jb + (r - 32);
      H8 v = z;
      if (j >= 0 && j < LDIM) v = *(const H8*)&hid[((size_t)((BDIM + b) * LDIM + j)) * HDIM + seg];
      *(H8*)&ll[r - 32][seg] = v;
    }
  }
  __syncthreads();
  float4 wp0 = wpart[0], wp1 = wpart[1];
  const float4 wsum = make_float4(wp0.x + wp1.x, wp0.y + wp1.y,
                                  wp0.z + wp1.z, wp0.w + wp1.w);

  // phase B: thread = one ii row x 4 jj cols (jlo, +8, +16, +24)
  const int ii = t >> 3;
  const int jlo = t & 7;
  const __half2 one2 = __float2half2_rn(1.0f);
  __half2 aE[4][4], aO[4][4];   // [jjgroup][k], even(i=0,1)/odd(i=2,3) octet halves
#pragma unroll
  for (int q = 0; q < 4; ++q)
#pragma unroll
    for (int k = 0; k < 4; ++k) {
      aE[q][k] = __float2half2_rn(0.f);
      aO[q][k] = __float2half2_rn(0.f);
    }

#define DO_JJ(Q, JJ)                                                          \
  {                                                                           \
    H8 l8 = *(const H8*)&ll[(JJ)][h];                                         \
    __half2 g0 = h2rcp(__hadd2(h2exp2(__hmul2(r8.p[0], l8.p[0])), one2));     \
    __half2 g1 = h2rcp(__hadd2(h2exp2(__hmul2(r8.p[1], l8.p[1])), one2));     \
    __half2 g2 = h2rcp(__hadd2(h2exp2(__hmul2(r8.p[2], l8.p[2])), one2));     \
    __half2 g3 = h2rcp(__hadd2(h2exp2(__hmul2(r8.p[3], l8.p[3])), one2));     \
    _Pragma("unroll")                                                         \
    for (int k = 0; k < 4; ++k) {                                             \
      aE[Q][k] = __hfma2(g0, wk[k].p[0], aE[Q][k]);                           \
      aE[Q][k] = __hfma2(g1, wk[k].p[1], aE[Q][k]);                           \
      aO[Q][k] = __hfma2(g2, wk[k].p[2], aO[Q][k]);                           \
      aO[Q][k] = __hfma2(g3, wk[k].p[3], aO[Q][k]);                           \
    }                                                                         \
  }

  for (int h = 0; h < HDIM; h += 8) {
    H8 r8 = *(const H8*)&rl[ii][h];
    H8 wk[4];
#pragma unroll
    for (int k = 0; k < 4; ++k) wk[k] = *(const H8*)&whl[k][h];
    DO_JJ(0, jlo)
    DO_JJ(1, jlo + 8)
    DO_JJ(2, jlo + 16)
    DO_JJ(3, jlo + 24)
  }
#undef DO_JJ

#pragma unroll
  for (int q = 0; q < 4; ++q) {
    float4 s;
    s.x = wsum.x + sum_h2(aE[q][0]) + sum_h2(aO[q][0]);
    s.y = wsum.y + sum_h2(aE[q][1]) + sum_h2(aO[q][1]);
    s.z = wsum.z + sum_h2(aE[q][2]) + sum_h2(aO[q][2]);
    s.w = wsum.w + sum_h2(aE[q][3]) + sum_h2(aO[q][3]);
    sl[ii][jlo + q * 8][0] = __floats2half2_rn(s.x, s.y);
    sl[ii][jlo + q * 8][1] = __floats2half2_rn(s.z, s.w);
  }
  __syncthreads();

  // phase C: y[i,j] = cb + s00(i-1,j-1)+s01(i-1,j)+s10(i,j-1)+s11(i,j); max
  float m = -INFINITY;
  const float cbv = cb[0];
  for (int p = t; p < 1024; p += 256) {
    int jj = p & 31, iy = p >> 5;
    int i = ib + iy, j = jb + jj;
    if (iy > 0 && jj > 0 && i < LDIM && j < LDIM) {
      float v = cbv + __low2float(sl[iy - 1][jj - 1][0])
                    + __high2float(sl[iy - 1][jj][0])
                    + __low2float(sl[iy][jj - 1][1])
                    + __high2float(sl[iy][jj][1]);
      m = fmaxf(m, v);
    }
  }
#pragma unroll
  for (int off = 32; off > 0; off >>= 1) m = fmaxf(m, __shfl_down(m, off, 64));
  if ((t & 63) == 0) wred[t >> 6] = m;
  __syncthreads();
  if (t == 0) {
    float mm = fmaxf(fmaxf(wred[0], wred[1]), fmaxf(wred[2], wred[3]));
    partial[((size_t)b * NT + blockIdx.y) * NT + blockIdx.x] = mm;
  }
}

// ---------------------------------------------------------------------------
// Kernel 3: reduce 17x17 partials per batch, sigmoid, write 4 outputs.
// ---------------------------------------------------------------------------
__global__ __launch_bounds__(64) void finalize(const float* __restrict__ partial,
                                               float* __restrict__ out) {
  const int b = blockIdx.x, t = threadIdx.x;
  float m = -INFINITY;
  for (int p = t; p < NT * NT; p += 64) m = fmaxf(m, partial[b * NT * NT + p]);
#pragma unroll
  for (int off = 32; off > 0; off >>= 1) m = fmaxf(m, __shfl_down(m, off, 64));
  if (t == 0) out[b] = 1.f / (1.f + expf(-m));
}

extern "C" void kernel_launch(void* const* d_in, const int* in_sizes, int n_in,
                              void* d_out, int out_size, void* d_ws, size_t ws_size,
                              hipStream_t stream) {
  const float* rec = (const float*)d_in[0];
  const float* lig = (const float*)d_in[1];
  const float* W1  = (const float*)d_in[2];
  const float* b1  = (const float*)d_in[3];
  const float* cw  = (const float*)d_in[4];   // (1,H,2,2) = float4 per h
  const float* cb  = (const float*)d_in[5];
  float* out = (float*)d_out;

  ushort_t* Wt    = (ushort_t*)d_ws;                    // 128x1024 f16 = 256 KB
  ushort_t* hid_h = Wt + (size_t)HDIM * EDIM;           // 4096x128 f16 = 1 MB
  float* partial  = (float*)(hid_h + (size_t)2 * BDIM * LDIM * HDIM);

  wcvt<<<dim3(64), 256, 0, stream>>>(W1, Wt);
  gemm_f16<<<dim3(2 * BDIM * LDIM / 16), 512, 0, stream>>>(rec, lig, Wt, b1, hid_h);
  bilinear_max<<<dim3(NT, NT, BDIM), 256, 0, stream>>>(hid_h, (const float4*)cw, cb, partial);
  finalize<<<dim3(BDIM), 64, 0, stream>>>(partial, out);
}

// Round 8
// 143.472 us; speedup vs baseline: 1.0359x; 1.0359x over previous
//
#include <hip/hip_runtime.h>
#include <hip/hip_fp16.h>
#include <math.h>

#define BDIM 4
#define LDIM 512
#define EDIM 1024
#define HDIM 128
#define TILE 31            // interior y-tile per block (s-grid is 32x32 with 1 halo)
#define NT   17            // 17*31 = 527 >= 512 tiles per spatial dim
#define K2   2.885390081777927f   // 2/ln(2): tanh(x) = 1 - 2/(exp2(K2*x)+1)

typedef unsigned short ushort_t;
typedef __attribute__((ext_vector_type(8))) _Float16 half8;
typedef __attribute__((ext_vector_type(4))) float f32x4;

struct __align__(16) H8 { __half2 p[4]; };
union HU { H8 h; half8 v; };

__device__ __forceinline__ float sum_h2(__half2 v) {
  return __low2float(v) + __high2float(v);
}

// ---------------------------------------------------------------------------
// Kernel 0: W1 (1024x128 f32, k-major) -> Wt (128x1024 f16, n-major).
// ---------------------------------------------------------------------------
__global__ __launch_bounds__(256) void wcvt(const float* __restrict__ W1,
                                            ushort_t* __restrict__ Wt) {
  const int g = (int)blockIdx.x * 256 + threadIdx.x;  // 0..16383
  const int n = g & 127, k8 = g >> 7;                 // k8: 0..127
  float v[8];
#pragma unroll
  for (int j = 0; j < 8; ++j) v[j] = W1[(size_t)(k8 * 8 + j) * HDIM + n];
  H8 o;
#pragma unroll
  for (int j = 0; j < 4; ++j) o.p[j] = __floats2half2_rn(v[2 * j], v[2 * j + 1]);
  *(H8*)&Wt[(size_t)n * EDIM + k8 * 8] = o;
}

// ---------------------------------------------------------------------------
// Kernel 1: hid32 += emb @ W1 (raw, no bias/relu) via f16 MFMA 16x16x32.
// NO LDS, NO barriers: each lane loads its A-frag (8 consecutive f32, cvt to
// f16) and B-frags (8 consecutive halves of Wt, L2-hot) directly from global.
// K-split x8: 2048 independent waves (512 blocks x 4), each = 16-row strip x
// 128 cols x K-slice 128 (4 chunks of 32); f32 atomicAdd epilogue into the
// pre-zeroed hid32. Fully compiler-pipelineable (no sync points).
// ---------------------------------------------------------------------------
__global__ __launch_bounds__(256) void gemm_partial(
    const float* __restrict__ rec, const float* __restrict__ lig,
    const ushort_t* __restrict__ Wt, float* __restrict__ hid32) {
  const int gw = (int)blockIdx.x * 4 + (threadIdx.x >> 6);  // 0..2047
  const int l = threadIdx.x & 63;
  const int strip = gw >> 3;          // 0..255 -> rows strip*16..+15
  const int ks = gw & 7;              // K-slice 0..7
  const int r0 = strip * 16;
  const float* abase = (r0 < BDIM * LDIM)
                           ? rec + (size_t)r0 * EDIM
                           : lig + (size_t)(r0 - BDIM * LDIM) * EDIM;
  const int m = l & 15, q = l >> 4;   // frag row, k-octet quad
  const int kb = ks * 128;

  f32x4 acc[8];
#pragma unroll
  for (int j = 0; j < 8; ++j) acc[j] = (f32x4){0.f, 0.f, 0.f, 0.f};

#pragma unroll
  for (int c = 0; c < 4; ++c) {
    const int k0 = kb + c * 32 + q * 8;
    float4 a_lo = *(const float4*)(abase + (size_t)m * EDIM + k0);
    float4 a_hi = *(const float4*)(abase + (size_t)m * EDIM + k0 + 4);
    HU au;
    au.h.p[0] = __floats2half2_rn(a_lo.x, a_lo.y);
    au.h.p[1] = __floats2half2_rn(a_lo.z, a_lo.w);
    au.h.p[2] = __floats2half2_rn(a_hi.x, a_hi.y);
    au.h.p[3] = __floats2half2_rn(a_hi.z, a_hi.w);
#pragma unroll
    for (int j = 0; j < 8; ++j) {
      half8 bf = *(const half8*)(Wt + (size_t)(16 * j + m) * EDIM + k0);
      acc[j] = __builtin_amdgcn_mfma_f32_16x16x32_f16(au.v, bf, acc[j], 0, 0, 0);
    }
  }

  // C/D: col = lane&15, row = (lane>>4)*4 + reg  [m89-verified]
#pragma unroll
  for (int j = 0; j < 8; ++j)
#pragma unroll
    for (int r = 0; r < 4; ++r)
      atomicAdd(&hid32[(size_t)(r0 + q * 4 + r) * HDIM + 16 * j + m], acc[j][r]);
}

// ---------------------------------------------------------------------------
// stage helper: hidden = relu(raw + bias) * scale, packed to 8 f16.
// ---------------------------------------------------------------------------
__device__ __forceinline__ H8 stage8(const float* __restrict__ hrow,
                                     const float* __restrict__ b1,
                                     int seg, float scale) {
  float4 v0 = *(const float4*)(hrow + seg);
  float4 v1 = *(const float4*)(hrow + seg + 4);
  float4 b0 = *(const float4*)(b1 + seg);
  float4 b4 = *(const float4*)(b1 + seg + 4);
  H8 o;
  o.p[0] = __floats2half2_rn(fmaxf(v0.x + b0.x, 0.f) * scale,
                             fmaxf(v0.y + b0.y, 0.f) * scale);
  o.p[1] = __floats2half2_rn(fmaxf(v0.z + b0.z, 0.f) * scale,
                             fmaxf(v0.w + b0.w, 0.f) * scale);
  o.p[2] = __floats2half2_rn(fmaxf(v1.x + b4.x, 0.f) * scale,
                             fmaxf(v1.y + b4.y, 0.f) * scale);
  o.p[3] = __floats2half2_rn(fmaxf(v1.z + b4.z, 0.f) * scale,
                             fmaxf(v1.w + b4.w, 0.f) * scale);
  return o;
}

// ---------------------------------------------------------------------------
// Kernel 2 (round-5 configuration, best measured): per 31x31 y-tile:
// s_k(p,q) = Wsum_k + sum_h (-2 w_k[h]) * g(p,q,h), g = rcp(1+exp2(K2*r*l)).
// Staging now reads raw hid32 and applies bias+relu+K2-scale+f16-cvt inline.
// ---------------------------------------------------------------------------
__global__ __launch_bounds__(256, 4) void bilinear_max(
    const float* __restrict__ hid32, const float* __restrict__ b1,
    const float4* __restrict__ cw4, const float* __restrict__ cb,
    float* __restrict__ partial) {
  __shared__ ushort_t rl[32][136];   // 272 B row stride
  __shared__ ushort_t ll[32][136];
  __shared__ __half whl[4][HDIM];    // -2*w_k[h] as f16, h-contiguous
  __shared__ float4 sl[32][33];      // f32 taps (round-5 layout)
  __shared__ float wred[4];
  __shared__ float4 wpart[2];

  const int t = threadIdx.x;
  const int b = blockIdx.z;
  const int ib = (int)blockIdx.y * TILE - 1;
  const int jb = (int)blockIdx.x * TILE - 1;

  if (t < HDIM) {
    float4 w4 = cw4[t];
    whl[0][t] = __float2half(-2.f * w4.x);
    whl[1][t] = __float2half(-2.f * w4.y);
    whl[2][t] = __float2half(-2.f * w4.z);
    whl[3][t] = __float2half(-2.f * w4.w);
    float4 ws = w4;
#pragma unroll
    for (int off = 32; off > 0; off >>= 1) {
      ws.x += __shfl_down(ws.x, off, 64);
      ws.y += __shfl_down(ws.y, off, 64);
      ws.z += __shfl_down(ws.z, off, 64);
      ws.w += __shfl_down(ws.w, off, 64);
    }
    if ((t & 63) == 0) wpart[t >> 6] = ws;
  }
  H8 z;
  z.p[0] = z.p[1] = z.p[2] = z.p[3] = __floats2half2_rn(0.f, 0.f);
  for (int p = t; p < 1024; p += 256) {   // 64 rows x 16 b128 segments
    int r = p >> 4, seg = (p & 15) * 8;
    if (r < 32) {
      int i = ib + r;
      H8 v = z;
      if (i >= 0 && i < LDIM)
        v = stage8(hid32 + (size_t)(b * LDIM + i) * HDIM, b1, seg, K2);
      *(H8*)&rl[r][seg] = v;
    } else {
      int j = jb + (r - 32);
      H8 v = z;
      if (j >= 0 && j < LDIM)
        v = stage8(hid32 + (size_t)((BDIM + b) * LDIM + j) * HDIM, b1, seg, 1.0f);
      *(H8*)&ll[r - 32][seg] = v;
    }
  }
  __syncthreads();
  float4 wp0 = wpart[0], wp1 = wpart[1];
  const float4 wsum = make_float4(wp0.x + wp1.x, wp0.y + wp1.y,
                                  wp0.z + wp1.z, wp0.w + wp1.w);

  // phase B: thread = one ii row x 4 jj cols (jlo, +8, +16, +24)
  const int ii = t >> 3;
  const int jlo = t & 7;
  const __half2 one2 = __float2half2_rn(1.0f);
  __half2 aE[4][4], aO[4][4];
#pragma unroll
  for (int q = 0; q < 4; ++q)
#pragma unroll
    for (int k = 0; k < 4; ++k) {
      aE[q][k] = __float2half2_rn(0.f);
      aO[q][k] = __float2half2_rn(0.f);
    }

#define DO_JJ(Q, JJ)                                                          \
  {                                                                           \
    H8 l8 = *(const H8*)&ll[(JJ)][h];                                         \
    __half2 g0 = h2rcp(__hadd2(h2exp2(__hmul2(r8.p[0], l8.p[0])), one2));     \
    __half2 g1 = h2rcp(__hadd2(h2exp2(__hmul2(r8.p[1], l8.p[1])), one2));     \
    __half2 g2 = h2rcp(__hadd2(h2exp2(__hmul2(r8.p[2], l8.p[2])), one2));     \
    __half2 g3 = h2rcp(__hadd2(h2exp2(__hmul2(r8.p[3], l8.p[3])), one2));     \
    _Pragma("unroll")                                                         \
    for (int k = 0; k < 4; ++k) {                                             \
      aE[Q][k] = __hfma2(g0, wk[k].p[0], aE[Q][k]);                           \
      aE[Q][k] = __hfma2(g1, wk[k].p[1], aE[Q][k]);                           \
      aO[Q][k] = __hfma2(g2, wk[k].p[2], aO[Q][k]);                           \
      aO[Q][k] = __hfma2(g3, wk[k].p[3], aO[Q][k]);                           \
    }                                                                         \
  }

  for (int h = 0; h < HDIM; h += 8) {
    H8 r8 = *(const H8*)&rl[ii][h];
    H8 wk[4];
#pragma unroll
    for (int k = 0; k < 4; ++k) wk[k] = *(const H8*)&whl[k][h];
    DO_JJ(0, jlo)
    DO_JJ(1, jlo + 8)
    DO_JJ(2, jlo + 16)
    DO_JJ(3, jlo + 24)
  }
#undef DO_JJ

#pragma unroll
  for (int q = 0; q < 4; ++q) {
    float4 s;
    s.x = wsum.x + sum_h2(aE[q][0]) + sum_h2(aO[q][0]);
    s.y = wsum.y + sum_h2(aE[q][1]) + sum_h2(aO[q][1]);
    s.z = wsum.z + sum_h2(aE[q][2]) + sum_h2(aO[q][2]);
    s.w = wsum.w + sum_h2(aE[q][3]) + sum_h2(aO[q][3]);
    sl[ii][jlo + q * 8] = s;
  }
  __syncthreads();

  // phase C: y[i,j] = cb + s00(i-1,j-1)+s01(i-1,j)+s10(i,j-1)+s11(i,j); max
  float m = -INFINITY;
  const float cbv = cb[0];
  for (int p = t; p < 1024; p += 256) {
    int jj = p & 31, iy = p >> 5;
    int i = ib + iy, j = jb + jj;
    if (iy > 0 && jj > 0 && i < LDIM && j < LDIM) {
      float v = cbv + sl[iy - 1][jj - 1].x + sl[iy - 1][jj].y
                    + sl[iy][jj - 1].z + sl[iy][jj].w;
      m = fmaxf(m, v);
    }
  }
#pragma unroll
  for (int off = 32; off > 0; off >>= 1) m = fmaxf(m, __shfl_down(m, off, 64));
  if ((t & 63) == 0) wred[t >> 6] = m;
  __syncthreads();
  if (t == 0) {
    float mm = fmaxf(fmaxf(wred[0], wred[1]), fmaxf(wred[2], wred[3]));
    partial[((size_t)b * NT + blockIdx.y) * NT + blockIdx.x] = mm;
  }
}

// ---------------------------------------------------------------------------
// Kernel 3: reduce 17x17 partials per batch, sigmoid, write 4 outputs.
// ---------------------------------------------------------------------------
__global__ __launch_bounds__(64) void finalize(const float* __restrict__ partial,
                                               float* __restrict__ out) {
  const int b = blockIdx.x, t = threadIdx.x;
  float m = -INFINITY;
  for (int p = t; p < NT * NT; p += 64) m = fmaxf(m, partial[b * NT * NT + p]);
#pragma unroll
  for (int off = 32; off > 0; off >>= 1) m = fmaxf(m, __shfl_down(m, off, 64));
  if (t == 0) out[b] = 1.f / (1.f + expf(-m));
}

extern "C" void kernel_launch(void* const* d_in, const int* in_sizes, int n_in,
                              void* d_out, int out_size, void* d_ws, size_t ws_size,
                              hipStream_t stream) {
  const float* rec = (const float*)d_in[0];
  const float* lig = (const float*)d_in[1];
  const float* W1  = (const float*)d_in[2];
  const float* b1  = (const float*)d_in[3];
  const float* cw  = (const float*)d_in[4];   // (1,H,2,2) = float4 per h
  const float* cb  = (const float*)d_in[5];
  float* out = (float*)d_out;

  ushort_t* Wt   = (ushort_t*)d_ws;                       // 128x1024 f16 = 256 KB
  float* hid32   = (float*)(Wt + (size_t)HDIM * EDIM);    // 4096x128 f32 = 2 MB
  float* partial = hid32 + (size_t)2 * BDIM * LDIM * HDIM;

  hipMemsetAsync(hid32, 0, (size_t)2 * BDIM * LDIM * HDIM * sizeof(float), stream);
  wcvt<<<dim3(64), 256, 0, stream>>>(W1, Wt);
  gemm_partial<<<dim3(512), 256, 0, stream>>>(rec, lig, Wt, hid32);
  bilinear_max<<<dim3(NT, NT, BDIM), 256, 0, stream>>>(hid32, b1, (const float4*)cw, cb, partial);
  finalize<<<dim3(BDIM), 64, 0, stream>>>(partial, out);
}